// Round 13
// baseline (275.658 us; speedup 1.0000x reference)
//
#include <hip/hip_runtime.h>
#include <hip/hip_fp16.h>

#define EMBED_DIM 64
#define NBMAX 1024          // max row buckets
#define RPB 128             // rows per bucket
#define RPB_SHIFT 7
#define CAP 6144            // slots per bucket (+32 sigma vs mean 4092), guarded
#define CHUNK 8192          // edges per WG (empirical best: r5/r11 ~76us;
                            // 4096 -> 93us, 2048 -> 130us from write amp)
#define SCAT_T 512
#define EPT (CHUNK / SCAT_T)
#define DBLK 4              // dim blocks: 16 dims x fp16 x 100K rows = 3.2MB
#define DPB 16              //   -> fits per-XCD 4MiB L2 during each gather pass

typedef float f32x8 __attribute__((ext_vector_type(8)));
typedef float f32x4 __attribute__((ext_vector_type(4)));

__device__ __forceinline__ int load_idx(const void* p, int e, bool i64) {
    return i64 ? (int)((const long long*)p)[e] : ((const int*)p)[e];
}

__device__ __forceinline__ float h2f(ushort u) {
    __half_raw hr; hr.x = u;
    return __half2float(__half(hr));
}

// ---------------------------------------------------------------------------
// Detect index dtype (int64 values < 2^17 -> odd u32 words all zero) and zero
// per-bucket cursors. One WG, every call.
// ---------------------------------------------------------------------------
__global__ __launch_bounds__(1024) void detect_zero_kernel(
    const unsigned int* __restrict__ rows_u32, int* __restrict__ base, int nb) {
    const int tid = threadIdx.x;
    if (tid == 0) {
        int nz = 0;
        for (int i = 1; i < 128; i += 2) nz += (rows_u32[i] != 0u);
        base[0] = (nz == 0) ? 1 : 0;
    }
    if (tid < nb) base[4 + tid] = 0;               // gcur
}

// ---------------------------------------------------------------------------
// x (f32, row-major N x 64) -> xq (fp16, dim-block-major: 4 blocks of N x 16).
// ---------------------------------------------------------------------------
__global__ __launch_bounds__(256) void xconv_kernel(
    const float* __restrict__ x, ushort* __restrict__ xq, int N) {
    int t = blockIdx.x * 256 + threadIdx.x;
    if (t >= N * 8) return;
    const int r = t >> 3, k = t & 7;
    float4 a = ((const float4*)x)[t * 2];
    float4 b = ((const float4*)x)[t * 2 + 1];
    ushort h[8];
    h[0] = __half_as_ushort(__float2half_rn(a.x));
    h[1] = __half_as_ushort(__float2half_rn(a.y));
    h[2] = __half_as_ushort(__float2half_rn(a.z));
    h[3] = __half_as_ushort(__float2half_rn(a.w));
    h[4] = __half_as_ushort(__float2half_rn(b.x));
    h[5] = __half_as_ushort(__float2half_rn(b.y));
    h[6] = __half_as_ushort(__float2half_rn(b.z));
    h[7] = __half_as_ushort(__float2half_rn(b.w));
    ushort* dst = xq + (size_t)(k >> 1) * N * DPB + (size_t)r * DPB + (k & 1) * 8;
    *(uint4*)dst = *(const uint4*)h;
}

// ---------------------------------------------------------------------------
// Phase 1: bin edges into slotted bucket array (bucket b owns recs[b*CAP..]).
// ---------------------------------------------------------------------------
__global__ __launch_bounds__(SCAT_T) void bscatter_kernel(
    const void* __restrict__ rows_p, const void* __restrict__ cols_p,
    const float* __restrict__ vals, int* __restrict__ gcur,
    uint2* __restrict__ recs, const int* __restrict__ flag_p, int n_edges) {
    __shared__ int h[NBMAX];
    __shared__ int base[NBMAX];
    const bool i64 = (*flag_p != 0);
    const int tid = threadIdx.x;
    const int c0 = blockIdx.x * CHUNK;
    int rloc[EPT];

    for (int i = tid; i < NBMAX; i += SCAT_T) h[i] = 0;
    __syncthreads();

    #pragma unroll
    for (int k = 0; k < EPT; ++k) {
        int e = c0 + k * SCAT_T + tid;
        int r = (e < n_edges) ? load_idx(rows_p, e, i64) : -1;
        rloc[k] = r;
        if (r >= 0) atomicAdd(&h[r >> RPB_SHIFT], 1);
    }
    __syncthreads();

    for (int i = tid; i < NBMAX; i += SCAT_T) {
        int c = h[i];
        base[i] = c ? (i * CAP + atomicAdd(&gcur[i], c)) : 0;
        h[i] = 0;                  // reuse as within-WG cursor
    }
    __syncthreads();

    #pragma unroll
    for (int k0 = 0; k0 < EPT; k0 += 4) {
        int cc[4]; float vv[4];
        #pragma unroll
        for (int j = 0; j < 4; ++j) {
            int e = c0 + (k0 + j) * SCAT_T + tid;
            if (rloc[k0 + j] >= 0) {
                cc[j] = load_idx(cols_p, e, i64);
                vv[j] = vals[e];
            }
        }
        #pragma unroll
        for (int j = 0; j < 4; ++j) {
            int r = rloc[k0 + j];
            if (r >= 0) {
                int b = r >> RPB_SHIFT;
                int pos = base[b] + atomicAdd(&h[b], 1);
                if (pos < (b + 1) * CAP)   // overflow guard
                    recs[pos] = make_uint2(
                        ((unsigned)(r & (RPB - 1)) << 20) | (unsigned)cc[j],
                        __float_as_uint(vv[j]));
            }
        }
    }
}

// ---------------------------------------------------------------------------
// Phase 2: per-bucket counting sort (128 row bins) into row-contiguous order.
// Emits split arrays rc[pos]=col (u32), rv[pos]=val (fp16), srange[row].
// ---------------------------------------------------------------------------
__global__ __launch_bounds__(512) void bsort_kernel(
    const int* __restrict__ gcur, const uint2* __restrict__ recs,
    unsigned* __restrict__ rc, ushort* __restrict__ rv,
    uint2* __restrict__ srange, int N) {
    __shared__ int cnt[RPB];
    __shared__ int scn[RPB];
    __shared__ int rbase[RPB];
    const int b = blockIdx.x;
    const int tid = threadIdx.x;
    const int s = b * CAP;
    int n = gcur[b];
    if (n > CAP) n = CAP;

    if (tid < RPB) cnt[tid] = 0;
    __syncthreads();

    for (int i = tid; i < n; i += 512)
        atomicAdd(&cnt[recs[s + i].x >> 20], 1);
    __syncthreads();

    if (tid < RPB) scn[tid] = cnt[tid];
    __syncthreads();
    for (int d = 1; d < RPB; d <<= 1) {
        int u = (tid < RPB && tid >= d) ? scn[tid - d] : 0;
        __syncthreads();
        if (tid < RPB) scn[tid] += u;
        __syncthreads();
    }
    if (tid < RPB) {
        int excl = scn[tid] - cnt[tid];
        rbase[tid] = excl;
        int row = b * RPB + tid;
        if (row < N) srange[row] = make_uint2(s + excl, s + excl + cnt[tid]);
        cnt[tid] = 0;              // reuse as cursor
    }
    __syncthreads();

    for (int i = tid; i < n; i += 512) {
        uint2 e = recs[s + i];
        int lr = e.x >> 20;
        int pos = s + rbase[lr] + atomicAdd(&cnt[lr], 1);
        rc[pos] = e.x & 0xFFFFFu;
        rv[pos] = __half_as_ushort(__float2half_rn(__uint_as_float(e.y)));
    }
}

// ---------------------------------------------------------------------------
// Phase 3 (x DBLK launches): gather one 16-dim block. 8 threads/row = 4
// dim-slots x 2 edge groups; each group takes a CONTIGUOUS half of the row's
// range (r12's stride-2 parity split halved load efficiency). Record streams
// (rc/rv/srange) use NONTEMPORAL loads so the 19.2MB/pass stream doesn't
// evict the 3.2MB x-slice from the per-XCD L2 (r12: slice+stream = 5.6MB
// > 4MB -> thrash; that was the missing 2x). x loads stay cached. Partials
// combined via __shfl_xor(4); epar==0 lanes do the NT store.
// ---------------------------------------------------------------------------
__global__ __launch_bounds__(256) void gather_dim_kernel(
    const uint2* __restrict__ srange, const unsigned* __restrict__ rc,
    const ushort* __restrict__ rv, const ushort* __restrict__ xqb,
    float* __restrict__ out, int N, int dbase) {
    int t = blockIdx.x * 256 + threadIdx.x;
    int row = t >> 3;
    if (row >= N) return;
    const int sub = t & 7;
    const int epar = sub >> 2;        // edge-half group (0/1)
    const int dslot = sub & 3;        // 4-dim slot within the 16-dim block

    unsigned long long rr =
        __builtin_nontemporal_load((const unsigned long long*)(srange + row));
    const int s = (int)(rr & 0xFFFFFFFFull);
    const int send = (int)(rr >> 32);
    const int hlen = (send - s) >> 1;
    int e     = epar ? (s + hlen) : s;
    const int e_end = epar ? send : (s + hlen);

    const ushort* xb = xqb + dslot * 4;
    f32x4 A = {};

    #define ACC4(C, V)                                                     \
        {                                                                  \
            uint2 u = *(const uint2*)(xb + (size_t)(C) * DPB);             \
            float2 f0 = __half22float2(*(const __half2*)&u.x);             \
            float2 f1 = __half22float2(*(const __half2*)&u.y);             \
            A[0] += (V) * f0.x; A[1] += (V) * f0.y;                        \
            A[2] += (V) * f1.x; A[3] += (V) * f1.y;                        \
        }

    for (; e + 3 < e_end; e += 4) {   // dense stride-1, 4 edges in flight
        unsigned c0 = __builtin_nontemporal_load(rc + e);
        unsigned c1 = __builtin_nontemporal_load(rc + e + 1);
        unsigned c2 = __builtin_nontemporal_load(rc + e + 2);
        unsigned c3 = __builtin_nontemporal_load(rc + e + 3);
        float v0 = h2f(__builtin_nontemporal_load(rv + e));
        float v1 = h2f(__builtin_nontemporal_load(rv + e + 1));
        float v2 = h2f(__builtin_nontemporal_load(rv + e + 2));
        float v3 = h2f(__builtin_nontemporal_load(rv + e + 3));
        ACC4(c0, v0); ACC4(c1, v1); ACC4(c2, v2); ACC4(c3, v3);
    }
    for (; e < e_end; ++e) {
        unsigned c = __builtin_nontemporal_load(rc + e);
        float v = h2f(__builtin_nontemporal_load(rv + e));
        ACC4(c, v);
    }
    #undef ACC4

    // combine the two edge-half partials: lane^4 = same row/dslot, other half
    A[0] += __shfl_xor(A[0], 4);
    A[1] += __shfl_xor(A[1], 4);
    A[2] += __shfl_xor(A[2], 4);
    A[3] += __shfl_xor(A[3], 4);

    if (epar == 0) {
        f32x4* op = (f32x4*)(out + (size_t)row * EMBED_DIM + dbase + dslot * 4);
        __builtin_nontemporal_store(A, op);
    }
}

// ---------------------------------------------------------------------------
// Fallback: atomic COO (f32) if workspace/shape constraints violated.
// ---------------------------------------------------------------------------
__global__ __launch_bounds__(256) void spmv_coo_kernel(
    const void* __restrict__ rows_p, const void* __restrict__ cols_p,
    const float* __restrict__ vals, const float* __restrict__ x,
    float* __restrict__ out, const int* __restrict__ flag_p, int n_edges) {
    const bool i64 = (*flag_p != 0);
    const int lane16 = threadIdx.x & 15;
    long long t      = (long long)blockIdx.x * blockDim.x + threadIdx.x;
    long long stride = (long long)gridDim.x * blockDim.x;
    long long total  = (long long)n_edges * 16;
    for (; t < total; t += stride) {
        int e = (int)(t >> 4);
        int r = load_idx(rows_p, e, i64);
        int c = load_idx(cols_p, e, i64);
        float v = vals[e];
        float4 xv = ((const float4*)(x + (long long)c * EMBED_DIM))[lane16];
        float* o = out + (long long)r * EMBED_DIM + lane16 * 4;
        unsafeAtomicAdd(o + 0, xv.x * v);
        unsafeAtomicAdd(o + 1, xv.y * v);
        unsafeAtomicAdd(o + 2, xv.z * v);
        unsafeAtomicAdd(o + 3, xv.w * v);
    }
}

extern "C" void kernel_launch(void* const* d_in, const int* in_sizes, int n_in,
                              void* d_out, int out_size, void* d_ws, size_t ws_size,
                              hipStream_t stream) {
    const float* x    = (const float*)d_in[0];
    const void*  rows = d_in[1];
    const void*  cols = d_in[2];
    const float* vals = (const float*)d_in[3];
    float* out = (float*)d_out;
    const int E = in_sizes[1];
    const int N = out_size / EMBED_DIM;
    const int NB = (N + RPB - 1) >> RPB_SHIFT;

    // Workspace: flag[4 ints] | gcur[NBMAX ints] | xq[DBLK*N*DPB ushort] |
    // srange[N uint2] | recs[NB*CAP uint2] | rc[NB*CAP u32] | rv[NB*CAP u16]
    int*      base   = (int*)d_ws;
    int*      flag   = base;
    int*      gcur   = base + 4;
    ushort*   xq     = (ushort*)(base + 4 + NBMAX);
    uint2*    srange = (uint2*)(xq + (size_t)DBLK * N * DPB);
    uint2*    recs   = srange + N;
    unsigned* rc     = (unsigned*)(recs + (size_t)NB * CAP);
    ushort*   rv     = (ushort*)(rc + (size_t)NB * CAP);
    const size_t needed = (size_t)(4 + NBMAX) * 4
                        + (size_t)DBLK * N * DPB * 2
                        + (size_t)N * 8
                        + (size_t)NB * CAP * (8 + 4 + 2);

    if (ws_size < needed || NB > NBMAX || N > (1 << 20) ||
        (size_t)NB * CAP < (size_t)E / 2) {
        detect_zero_kernel<<<1, 1024, 0, stream>>>((const unsigned int*)rows,
                                                   base, 0);
        (void)hipMemsetAsync(d_out, 0, (size_t)out_size * sizeof(float), stream);
        spmv_coo_kernel<<<8192, 256, 0, stream>>>(rows, cols, vals, x, out,
                                                  flag, E);
        return;
    }

    detect_zero_kernel<<<1, 1024, 0, stream>>>((const unsigned int*)rows,
                                               base, NB);
    xconv_kernel<<<(N * 8 + 255) / 256, 256, 0, stream>>>(x, xq, N);
    const int grid_c = (E + CHUNK - 1) / CHUNK;
    bscatter_kernel<<<grid_c, SCAT_T, 0, stream>>>(rows, cols, vals, gcur,
                                                   recs, flag, E);
    bsort_kernel<<<NB, 512, 0, stream>>>(gcur, recs, rc, rv, srange, N);
    const int grid_g = (N * 8 + 255) / 256;
    for (int b = 0; b < DBLK; ++b)
        gather_dim_kernel<<<grid_g, 256, 0, stream>>>(
            srange, rc, rv, xq + (size_t)b * N * DPB, out, N, b * DPB);
}

// Round 14
// 213.622 us; speedup vs baseline: 1.2904x; 1.2904x over previous
//
#include <hip/hip_runtime.h>
#include <hip/hip_fp16.h>

#define EMBED_DIM 64
#define NBMAX 1024          // max row buckets
#define RPB 128             // rows per bucket
#define RPB_SHIFT 7
#define CAP 7168            // slots/bucket; mean fill 4092 + align-waste ~1370
                            // (391 WGs x 3.5 wasted/touched-bucket); CAP*8B is
                            // 64B-line divisible so aligned runs stay aligned
#define CHUNK 8192          // edges per WG (empirical best r5/r11/r13)
#define SCAT_T 512
#define EPT (CHUNK / SCAT_T)
#define SENTINEL 0xFFFFFFFFu

typedef float f32x8 __attribute__((ext_vector_type(8)));
typedef float f32x4 __attribute__((ext_vector_type(4)));

__device__ __forceinline__ int load_idx(const void* p, int e, bool i64) {
    return i64 ? (int)((const long long*)p)[e] : ((const int*)p)[e];
}

__device__ __forceinline__ float h2f(ushort u) {
    __half_raw hr; hr.x = u;
    return __half2float(__half(hr));
}

// ---------------------------------------------------------------------------
// Detect index dtype (int64 values < 2^17 -> odd u32 words all zero) and zero
// per-bucket cursors. One WG, every call.
// ---------------------------------------------------------------------------
__global__ __launch_bounds__(1024) void detect_zero_kernel(
    const unsigned int* __restrict__ rows_u32, int* __restrict__ base, int nb) {
    const int tid = threadIdx.x;
    if (tid == 0) {
        int nz = 0;
        for (int i = 1; i < 128; i += 2) nz += (rows_u32[i] != 0u);
        base[0] = (nz == 0) ? 1 : 0;
    }
    if (tid < nb) base[4 + tid] = 0;               // gcur
}

// ---------------------------------------------------------------------------
// x (f32) -> xh (fp16, row-major N x 64). r7 layout (best measured gather).
// ---------------------------------------------------------------------------
__global__ __launch_bounds__(256) void xconv_kernel(
    const float* __restrict__ x, ushort* __restrict__ xh, int n8) {
    int i = blockIdx.x * 256 + threadIdx.x;
    if (i >= n8) return;
    float4 a = ((const float4*)x)[i * 2];
    float4 b = ((const float4*)x)[i * 2 + 1];
    ushort h[8];
    h[0] = __half_as_ushort(__float2half_rn(a.x));
    h[1] = __half_as_ushort(__float2half_rn(a.y));
    h[2] = __half_as_ushort(__float2half_rn(a.z));
    h[3] = __half_as_ushort(__float2half_rn(a.w));
    h[4] = __half_as_ushort(__float2half_rn(b.x));
    h[5] = __half_as_ushort(__float2half_rn(b.y));
    h[6] = __half_as_ushort(__float2half_rn(b.z));
    h[7] = __half_as_ushort(__float2half_rn(b.w));
    ((uint4*)xh)[i] = *(const uint4*)h;
}

// ---------------------------------------------------------------------------
// Phase 1: bin edges into slotted buckets with LINE-ALIGNED per-WG runs.
// Reservations rounded up to 8 records (64B); the unused tail of each run is
// sentinel-filled. Every 64B line of recs is therefore written entirely by
// ONE workgroup -> no cross-XCD partial-line RFO (r5..r13 measured 3x write
// amplification, 78MB for a 25.6MB payload, and ~1.2TB/s effective).
// ---------------------------------------------------------------------------
__global__ __launch_bounds__(SCAT_T) void bscatter_kernel(
    const void* __restrict__ rows_p, const void* __restrict__ cols_p,
    const float* __restrict__ vals, int* __restrict__ gcur,
    uint2* __restrict__ recs, const int* __restrict__ flag_p, int n_edges) {
    __shared__ int h[NBMAX];
    __shared__ int base[NBMAX];
    const bool i64 = (*flag_p != 0);
    const int tid = threadIdx.x;
    const int c0 = blockIdx.x * CHUNK;
    int rloc[EPT];

    for (int i = tid; i < NBMAX; i += SCAT_T) h[i] = 0;
    __syncthreads();

    #pragma unroll
    for (int k = 0; k < EPT; ++k) {
        int e = c0 + k * SCAT_T + tid;
        int r = (e < n_edges) ? load_idx(rows_p, e, i64) : -1;
        rloc[k] = r;
        if (r >= 0) atomicAdd(&h[r >> RPB_SHIFT], 1);
    }
    __syncthreads();

    for (int i = tid; i < NBMAX; i += SCAT_T) {
        int c = h[i];
        int ca = (c + 7) & ~7;                  // line-aligned reservation
        base[i] = c ? (i * CAP + atomicAdd(&gcur[i], ca)) : 0;
        h[i] = 0;                               // reuse as within-WG cursor
    }
    __syncthreads();

    #pragma unroll
    for (int k0 = 0; k0 < EPT; k0 += 4) {
        int cc[4]; float vv[4];
        #pragma unroll
        for (int j = 0; j < 4; ++j) {
            int e = c0 + (k0 + j) * SCAT_T + tid;
            if (rloc[k0 + j] >= 0) {
                cc[j] = load_idx(cols_p, e, i64);
                vv[j] = vals[e];
            }
        }
        #pragma unroll
        for (int j = 0; j < 4; ++j) {
            int r = rloc[k0 + j];
            if (r >= 0) {
                int b = r >> RPB_SHIFT;
                int pos = base[b] + atomicAdd(&h[b], 1);
                if (pos < (b + 1) * CAP)        // overflow guard
                    recs[pos] = make_uint2(
                        ((unsigned)(r & (RPB - 1)) << 20) | (unsigned)cc[j],
                        __float_as_uint(vv[j]));
            }
        }
    }
    __syncthreads();

    // Fill each run's alignment tail with sentinels (same line, same WG).
    for (int i = tid; i < NBMAX; i += SCAT_T) {
        int c = h[i];
        if (c > 0) {
            int ca = (c + 7) & ~7;
            for (int j = c; j < ca; ++j) {
                int pos = base[i] + j;
                if (pos < (i + 1) * CAP)
                    recs[pos] = make_uint2(SENTINEL, 0u);
            }
        }
    }
}

// ---------------------------------------------------------------------------
// Phase 2: per-bucket counting sort (128 row bins), sentinel-skipping.
// Emits split rc[pos]=col (u32), rv[pos]=val (fp16), srange[row]={start,end}.
// ---------------------------------------------------------------------------
__global__ __launch_bounds__(512) void bsort_kernel(
    const int* __restrict__ gcur, const uint2* __restrict__ recs,
    unsigned* __restrict__ rc, ushort* __restrict__ rv,
    uint2* __restrict__ srange, int N) {
    __shared__ int cnt[RPB];
    __shared__ int scn[RPB];
    __shared__ int rbase[RPB];
    const int b = blockIdx.x;
    const int tid = threadIdx.x;
    const int s = b * CAP;
    int n = gcur[b];
    if (n > CAP) n = CAP;

    if (tid < RPB) cnt[tid] = 0;
    __syncthreads();

    for (int i = tid; i < n; i += 512) {
        unsigned lr = recs[s + i].x >> 20;
        if (lr < RPB) atomicAdd(&cnt[lr], 1);   // skip sentinels
    }
    __syncthreads();

    if (tid < RPB) scn[tid] = cnt[tid];
    __syncthreads();
    for (int d = 1; d < RPB; d <<= 1) {
        int u = (tid < RPB && tid >= d) ? scn[tid - d] : 0;
        __syncthreads();
        if (tid < RPB) scn[tid] += u;
        __syncthreads();
    }
    if (tid < RPB) {
        int excl = scn[tid] - cnt[tid];
        rbase[tid] = excl;
        int row = b * RPB + tid;
        if (row < N) srange[row] = make_uint2(s + excl, s + excl + cnt[tid]);
        cnt[tid] = 0;              // reuse as cursor
    }
    __syncthreads();

    for (int i = tid; i < n; i += 512) {
        uint2 e = recs[s + i];
        unsigned lr = e.x >> 20;
        if (lr < RPB) {
            int pos = s + rbase[lr] + atomicAdd(&cnt[lr], 1);
            rc[pos] = e.x & 0xFFFFFu;
            rv[pos] = __half_as_ushort(__float2half_rn(__uint_as_float(e.y)));
        }
    }
}

// ---------------------------------------------------------------------------
// Phase 3: single-pass row-parallel gather (round-7 form, the measured best).
// 8 lanes per row; each lane owns 8 dims (one uint4 of fp16 per edge), f32
// accumulation, 4-deep unroll, cached loads (NT loads regressed: they break
// the cache broadcast of rc/rv across the row's lanes -- r13). Two coalesced
// float4 stores per lane.
// ---------------------------------------------------------------------------
__global__ __launch_bounds__(256) void gather_kernel(
    const uint2* __restrict__ srange, const unsigned* __restrict__ rc,
    const ushort* __restrict__ rv, const ushort* __restrict__ xh,
    float* __restrict__ out, int N) {
    int t = blockIdx.x * blockDim.x + threadIdx.x;
    int row = t >> 3;
    if (row >= N) return;
    const int lane = t & 7;

    uint2 rg = srange[row];
    int e = (int)rg.x;
    const int e_end = (int)rg.y;
    f32x8 A = {};

    #define ACC8(U, V)                                                     \
        {                                                                  \
            float2 f0 = __half22float2(*(const __half2*)&(U).x);           \
            float2 f1 = __half22float2(*(const __half2*)&(U).y);           \
            float2 f2 = __half22float2(*(const __half2*)&(U).z);           \
            float2 f3 = __half22float2(*(const __half2*)&(U).w);           \
            A[0] += (V) * f0.x; A[1] += (V) * f0.y;                        \
            A[2] += (V) * f1.x; A[3] += (V) * f1.y;                        \
            A[4] += (V) * f2.x; A[5] += (V) * f2.y;                        \
            A[6] += (V) * f3.x; A[7] += (V) * f3.y;                        \
        }

    for (; e + 4 <= e_end; e += 4) {
        unsigned c0 = rc[e],     c1 = rc[e + 1];
        unsigned c2 = rc[e + 2], c3 = rc[e + 3];
        float v0 = h2f(rv[e]),     v1 = h2f(rv[e + 1]);
        float v2 = h2f(rv[e + 2]), v3 = h2f(rv[e + 3]);
        uint4 a0 = ((const uint4*)(xh + (size_t)c0 * EMBED_DIM))[lane];
        uint4 a1 = ((const uint4*)(xh + (size_t)c1 * EMBED_DIM))[lane];
        uint4 a2 = ((const uint4*)(xh + (size_t)c2 * EMBED_DIM))[lane];
        uint4 a3 = ((const uint4*)(xh + (size_t)c3 * EMBED_DIM))[lane];
        ACC8(a0, v0); ACC8(a1, v1); ACC8(a2, v2); ACC8(a3, v3);
    }
    for (; e < e_end; ++e) {
        unsigned c0 = rc[e];
        uint4 a0 = ((const uint4*)(xh + (size_t)c0 * EMBED_DIM))[lane];
        ACC8(a0, h2f(rv[e]));
    }
    #undef ACC8

    f32x4 o0 = {A[0], A[1], A[2], A[3]};
    f32x4 o1 = {A[4], A[5], A[6], A[7]};
    f32x4* op = (f32x4*)(out + (size_t)row * EMBED_DIM) + lane * 2;
    __builtin_nontemporal_store(o0, op);
    __builtin_nontemporal_store(o1, op + 1);
}

// ---------------------------------------------------------------------------
// Fallback: atomic COO (f32) if workspace/shape constraints violated.
// ---------------------------------------------------------------------------
__global__ __launch_bounds__(256) void spmv_coo_kernel(
    const void* __restrict__ rows_p, const void* __restrict__ cols_p,
    const float* __restrict__ vals, const float* __restrict__ x,
    float* __restrict__ out, const int* __restrict__ flag_p, int n_edges) {
    const bool i64 = (*flag_p != 0);
    const int lane16 = threadIdx.x & 15;
    long long t      = (long long)blockIdx.x * blockDim.x + threadIdx.x;
    long long stride = (long long)gridDim.x * blockDim.x;
    long long total  = (long long)n_edges * 16;
    for (; t < total; t += stride) {
        int e = (int)(t >> 4);
        int r = load_idx(rows_p, e, i64);
        int c = load_idx(cols_p, e, i64);
        float v = vals[e];
        float4 xv = ((const float4*)(x + (long long)c * EMBED_DIM))[lane16];
        float* o = out + (long long)r * EMBED_DIM + lane16 * 4;
        unsafeAtomicAdd(o + 0, xv.x * v);
        unsafeAtomicAdd(o + 1, xv.y * v);
        unsafeAtomicAdd(o + 2, xv.z * v);
        unsafeAtomicAdd(o + 3, xv.w * v);
    }
}

extern "C" void kernel_launch(void* const* d_in, const int* in_sizes, int n_in,
                              void* d_out, int out_size, void* d_ws, size_t ws_size,
                              hipStream_t stream) {
    const float* x    = (const float*)d_in[0];
    const void*  rows = d_in[1];
    const void*  cols = d_in[2];
    const float* vals = (const float*)d_in[3];
    float* out = (float*)d_out;
    const int E = in_sizes[1];
    const int N = out_size / EMBED_DIM;
    const int NB = (N + RPB - 1) >> RPB_SHIFT;

    // Workspace: flag[4 ints] | gcur[NBMAX ints] | xh[N*64 ushort] |
    // srange[N uint2] | recs[NB*CAP uint2] | rc[NB*CAP u32] | rv[NB*CAP u16]
    int*      base   = (int*)d_ws;
    int*      flag   = base;
    int*      gcur   = base + 4;
    ushort*   xh     = (ushort*)(base + 4 + NBMAX);
    uint2*    srange = (uint2*)(xh + (size_t)N * EMBED_DIM);
    uint2*    recs   = srange + N;
    unsigned* rc     = (unsigned*)(recs + (size_t)NB * CAP);
    ushort*   rv     = (ushort*)(rc + (size_t)NB * CAP);
    const size_t needed = (size_t)(4 + NBMAX) * 4
                        + (size_t)N * EMBED_DIM * 2
                        + (size_t)N * 8
                        + (size_t)NB * CAP * (8 + 4 + 2);

    if (ws_size < needed || NB > NBMAX || N > (1 << 20) ||
        (size_t)NB * CAP < (size_t)E / 2) {
        detect_zero_kernel<<<1, 1024, 0, stream>>>((const unsigned int*)rows,
                                                   base, 0);
        (void)hipMemsetAsync(d_out, 0, (size_t)out_size * sizeof(float), stream);
        spmv_coo_kernel<<<8192, 256, 0, stream>>>(rows, cols, vals, x, out,
                                                  flag, E);
        return;
    }

    detect_zero_kernel<<<1, 1024, 0, stream>>>((const unsigned int*)rows,
                                               base, NB);
    xconv_kernel<<<(N * 8 + 255) / 256, 256, 0, stream>>>(x, xh, N * 8);
    const int grid_c = (E + CHUNK - 1) / CHUNK;
    bscatter_kernel<<<grid_c, SCAT_T, 0, stream>>>(rows, cols, vals, gcur,
                                                   recs, flag, E);
    bsort_kernel<<<NB, 512, 0, stream>>>(gcur, recs, rc, rv, srange, N);
    const int grid_g = (N * 8 + 255) / 256;
    gather_kernel<<<grid_g, 256, 0, stream>>>(srange, rc, rv, xh, out, N);
}

// Round 15
// 151.896 us; speedup vs baseline: 1.8148x; 1.4064x over previous
//
#include <hip/hip_runtime.h>
#include <hip/hip_fp16.h>

#define EMBED_DIM 64
#define NBMAX 1024          // max row buckets
#define RPB 128             // rows per bucket
#define RPB_SHIFT 7
#define CAP 6144            // slots/bucket: mean aligned fill ~5474, +8 sigma
#define CHUNK 8192          // edges per WG (empirical best r5/r11/r13)
#define SCAT_T 512
#define EPT (CHUNK / SCAT_T)
#define SENTINEL_KEY 0xFFFFFFFFu   // lr bits = 0xFFF >= RPB -> skipped in bsort

typedef float f32x8 __attribute__((ext_vector_type(8)));
typedef float f32x4 __attribute__((ext_vector_type(4)));

__device__ __forceinline__ int load_idx(const void* p, int e, bool i64) {
    return i64 ? (int)((const long long*)p)[e] : ((const int*)p)[e];
}

__device__ __forceinline__ float h2f(ushort u) {
    __half_raw hr; hr.x = u;
    return __half2float(__half(hr));
}

static inline size_t align_up(size_t v, size_t a) { return (v + a - 1) & ~(a - 1); }

// ---------------------------------------------------------------------------
// Detect index dtype (int64 values < 2^17 -> odd u32 words all zero) and zero
// per-bucket cursors. One WG, every call.
// ---------------------------------------------------------------------------
__global__ __launch_bounds__(1024) void detect_zero_kernel(
    const unsigned int* __restrict__ rows_u32, int* __restrict__ flag,
    int* __restrict__ gcur, int nb) {
    const int tid = threadIdx.x;
    if (tid == 0) {
        int nz = 0;
        for (int i = 1; i < 128; i += 2) nz += (rows_u32[i] != 0u);
        *flag = (nz == 0) ? 1 : 0;
    }
    if (tid < nb) gcur[tid] = 0;
}

// ---------------------------------------------------------------------------
// x (f32) -> xh (fp16, row-major N x 64). Round-7 layout (measured-best
// gather source). Output err ~0.05 << threshold 0.3975.
// ---------------------------------------------------------------------------
__global__ __launch_bounds__(256) void xconv_kernel(
    const float* __restrict__ x, ushort* __restrict__ xh, int n8) {
    int i = blockIdx.x * 256 + threadIdx.x;
    if (i >= n8) return;
    float4 a = ((const float4*)x)[i * 2];
    float4 b = ((const float4*)x)[i * 2 + 1];
    ushort h[8];
    h[0] = __half_as_ushort(__float2half_rn(a.x));
    h[1] = __half_as_ushort(__float2half_rn(a.y));
    h[2] = __half_as_ushort(__float2half_rn(a.z));
    h[3] = __half_as_ushort(__float2half_rn(a.w));
    h[4] = __half_as_ushort(__float2half_rn(b.x));
    h[5] = __half_as_ushort(__float2half_rn(b.y));
    h[6] = __half_as_ushort(__float2half_rn(b.z));
    h[7] = __half_as_ushort(__float2half_rn(b.w));
    ((uint4*)xh)[i] = *(const uint4*)h;
}

// ---------------------------------------------------------------------------
// Phase 1: bin edges into slotted buckets with LINE-ALIGNED per-WG runs.
// Reservations rounded to 8 records (64B); run tails sentinel-filled. With
// recs 256B-aligned (r14's attempt was silently 16B-misaligned -- offset
// 13,604,112 in d_ws!), each 64B line is written wholly by ONE workgroup ->
// no cross-XCD partial-line RFO on the 26-34MB record scatter.
// ---------------------------------------------------------------------------
__global__ __launch_bounds__(SCAT_T) void bscatter_kernel(
    const void* __restrict__ rows_p, const void* __restrict__ cols_p,
    const float* __restrict__ vals, int* __restrict__ gcur,
    uint2* __restrict__ recs, const int* __restrict__ flag_p, int n_edges) {
    __shared__ int h[NBMAX];
    __shared__ int base[NBMAX];
    const bool i64 = (*flag_p != 0);
    const int tid = threadIdx.x;
    const int c0 = blockIdx.x * CHUNK;
    int rloc[EPT];

    for (int i = tid; i < NBMAX; i += SCAT_T) h[i] = 0;
    __syncthreads();

    #pragma unroll
    for (int k = 0; k < EPT; ++k) {
        int e = c0 + k * SCAT_T + tid;
        int r = (e < n_edges) ? load_idx(rows_p, e, i64) : -1;
        rloc[k] = r;
        if (r >= 0) atomicAdd(&h[r >> RPB_SHIFT], 1);
    }
    __syncthreads();

    for (int i = tid; i < NBMAX; i += SCAT_T) {
        int c = h[i];
        int ca = (c + 7) & ~7;                  // 64B-aligned reservation
        base[i] = c ? (i * CAP + atomicAdd(&gcur[i], ca)) : 0;
        h[i] = 0;                               // reuse as within-WG cursor
    }
    __syncthreads();

    #pragma unroll
    for (int k0 = 0; k0 < EPT; k0 += 4) {
        int cc[4]; float vv[4];
        #pragma unroll
        for (int j = 0; j < 4; ++j) {
            int e = c0 + (k0 + j) * SCAT_T + tid;
            if (rloc[k0 + j] >= 0) {
                cc[j] = load_idx(cols_p, e, i64);
                vv[j] = vals[e];
            }
        }
        #pragma unroll
        for (int j = 0; j < 4; ++j) {
            int r = rloc[k0 + j];
            if (r >= 0) {
                int b = r >> RPB_SHIFT;
                int pos = base[b] + atomicAdd(&h[b], 1);
                if (pos < (b + 1) * CAP)        // overflow guard
                    recs[pos] = make_uint2(
                        ((unsigned)(r & (RPB - 1)) << 20) | (unsigned)cc[j],
                        __float_as_uint(vv[j]));
            }
        }
    }
    __syncthreads();

    // Fill each run's alignment tail with sentinels (same line, same WG).
    for (int i = tid; i < NBMAX; i += SCAT_T) {
        int c = h[i];
        if (c > 0) {
            int ca = (c + 7) & ~7;
            for (int j = c; j < ca; ++j) {
                int pos = base[i] + j;
                if (pos < (i + 1) * CAP)
                    recs[pos] = make_uint2(SENTINEL_KEY, 0u);
            }
        }
    }
}

// ---------------------------------------------------------------------------
// Phase 2: per-bucket counting sort (128 row bins), sentinel-skipping.
// Round-7 output form: recs2[pos] = {col, val_f32}, srange[row]={start,end}.
// ---------------------------------------------------------------------------
__global__ __launch_bounds__(512) void bsort_kernel(
    const int* __restrict__ gcur, const uint2* __restrict__ recs,
    uint2* __restrict__ recs2, uint2* __restrict__ srange, int N) {
    __shared__ int cnt[RPB];
    __shared__ int scn[RPB];
    __shared__ int rbase[RPB];
    const int b = blockIdx.x;
    const int tid = threadIdx.x;
    const int s = b * CAP;
    int n = gcur[b];
    if (n > CAP) n = CAP;

    if (tid < RPB) cnt[tid] = 0;
    __syncthreads();

    for (int i = tid; i < n; i += 512) {
        unsigned lr = recs[s + i].x >> 20;
        if (lr < RPB) atomicAdd(&cnt[lr], 1);   // skip sentinels
    }
    __syncthreads();

    if (tid < RPB) scn[tid] = cnt[tid];
    __syncthreads();
    for (int d = 1; d < RPB; d <<= 1) {
        int u = (tid < RPB && tid >= d) ? scn[tid - d] : 0;
        __syncthreads();
        if (tid < RPB) scn[tid] += u;
        __syncthreads();
    }
    if (tid < RPB) {
        int excl = scn[tid] - cnt[tid];
        rbase[tid] = excl;
        int row = b * RPB + tid;
        if (row < N) srange[row] = make_uint2(s + excl, s + excl + cnt[tid]);
        cnt[tid] = 0;              // reuse as cursor
    }
    __syncthreads();

    for (int i = tid; i < n; i += 512) {
        uint2 e = recs[s + i];
        unsigned lr = e.x >> 20;
        if (lr < RPB) {
            int pos = s + rbase[lr] + atomicAdd(&cnt[lr], 1);
            recs2[pos] = make_uint2(e.x & 0xFFFFFu, e.y);
        }
    }
}

// ---------------------------------------------------------------------------
// Phase 3: single-pass row-parallel gather -- exact round-7 form (measured
// best: 103.6us, 3.6TB/s L2-miss service). 8 lanes/row, one uint4 (8 fp16
// dims) per edge per lane, f32 accumulation, 4-deep unroll, cached loads.
// ---------------------------------------------------------------------------
__global__ __launch_bounds__(256) void gather_kernel(
    const uint2* __restrict__ srange, const uint2* __restrict__ recs2,
    const ushort* __restrict__ xh, float* __restrict__ out, int N) {
    int t = blockIdx.x * blockDim.x + threadIdx.x;
    int row = t >> 3;
    if (row >= N) return;
    const int lane = t & 7;

    uint2 rg = srange[row];
    int e = (int)rg.x;
    const int e_end = (int)rg.y;
    f32x8 A = {};

    #define ACC8(U, V)                                                     \
        {                                                                  \
            float2 f0 = __half22float2(*(const __half2*)&(U).x);           \
            float2 f1 = __half22float2(*(const __half2*)&(U).y);           \
            float2 f2 = __half22float2(*(const __half2*)&(U).z);           \
            float2 f3 = __half22float2(*(const __half2*)&(U).w);           \
            A[0] += (V) * f0.x; A[1] += (V) * f0.y;                        \
            A[2] += (V) * f1.x; A[3] += (V) * f1.y;                        \
            A[4] += (V) * f2.x; A[5] += (V) * f2.y;                        \
            A[6] += (V) * f3.x; A[7] += (V) * f3.y;                        \
        }

    for (; e + 4 <= e_end; e += 4) {
        uint2 r0 = recs2[e],     r1 = recs2[e + 1];
        uint2 r2 = recs2[e + 2], r3 = recs2[e + 3];
        uint4 a0 = ((const uint4*)(xh + (size_t)r0.x * EMBED_DIM))[lane];
        uint4 a1 = ((const uint4*)(xh + (size_t)r1.x * EMBED_DIM))[lane];
        uint4 a2 = ((const uint4*)(xh + (size_t)r2.x * EMBED_DIM))[lane];
        uint4 a3 = ((const uint4*)(xh + (size_t)r3.x * EMBED_DIM))[lane];
        float v0 = __uint_as_float(r0.y), v1 = __uint_as_float(r1.y);
        float v2 = __uint_as_float(r2.y), v3 = __uint_as_float(r3.y);
        ACC8(a0, v0); ACC8(a1, v1); ACC8(a2, v2); ACC8(a3, v3);
    }
    for (; e < e_end; ++e) {
        uint2 r0 = recs2[e];
        uint4 a0 = ((const uint4*)(xh + (size_t)r0.x * EMBED_DIM))[lane];
        ACC8(a0, __uint_as_float(r0.y));
    }
    #undef ACC8

    f32x4 o0 = {A[0], A[1], A[2], A[3]};
    f32x4 o1 = {A[4], A[5], A[6], A[7]};
    f32x4* op = (f32x4*)(out + (size_t)row * EMBED_DIM) + lane * 2;
    __builtin_nontemporal_store(o0, op);
    __builtin_nontemporal_store(o1, op + 1);
}

// ---------------------------------------------------------------------------
// Fallback: atomic COO (f32) if workspace/shape constraints violated.
// ---------------------------------------------------------------------------
__global__ __launch_bounds__(256) void spmv_coo_kernel(
    const void* __restrict__ rows_p, const void* __restrict__ cols_p,
    const float* __restrict__ vals, const float* __restrict__ x,
    float* __restrict__ out, const int* __restrict__ flag_p, int n_edges) {
    const bool i64 = (*flag_p != 0);
    const int lane16 = threadIdx.x & 15;
    long long t      = (long long)blockIdx.x * blockDim.x + threadIdx.x;
    long long stride = (long long)gridDim.x * blockDim.x;
    long long total  = (long long)n_edges * 16;
    for (; t < total; t += stride) {
        int e = (int)(t >> 4);
        int r = load_idx(rows_p, e, i64);
        int c = load_idx(cols_p, e, i64);
        float v = vals[e];
        float4 xv = ((const float4*)(x + (long long)c * EMBED_DIM))[lane16];
        float* o = out + (long long)r * EMBED_DIM + lane16 * 4;
        unsafeAtomicAdd(o + 0, xv.x * v);
        unsafeAtomicAdd(o + 1, xv.y * v);
        unsafeAtomicAdd(o + 2, xv.z * v);
        unsafeAtomicAdd(o + 3, xv.w * v);
    }
}

extern "C" void kernel_launch(void* const* d_in, const int* in_sizes, int n_in,
                              void* d_out, int out_size, void* d_ws, size_t ws_size,
                              hipStream_t stream) {
    const float* x    = (const float*)d_in[0];
    const void*  rows = d_in[1];
    const void*  cols = d_in[2];
    const float* vals = (const float*)d_in[3];
    float* out = (float*)d_out;
    const int E = in_sizes[1];
    const int N = out_size / EMBED_DIM;
    const int NB = (N + RPB - 1) >> RPB_SHIFT;

    // Workspace layout, every section 256B-aligned (recs alignment is the
    // point of this round: r14's runs were 16B off and straddled lines).
    char* ws = (char*)d_ws;
    size_t off = 0;
    int* flag = (int*)(ws + off);            off += 16;
    int* gcur = (int*)(ws + off);            off += (size_t)NBMAX * 4;
    off = align_up(off, 256);
    ushort* xh = (ushort*)(ws + off);        off += (size_t)N * EMBED_DIM * 2;
    off = align_up(off, 256);
    uint2* srange = (uint2*)(ws + off);      off += (size_t)N * 8;
    off = align_up(off, 256);
    uint2* recs = (uint2*)(ws + off);        off += (size_t)NB * CAP * 8;
    off = align_up(off, 256);
    uint2* recs2 = (uint2*)(ws + off);       off += (size_t)NB * CAP * 8;
    const size_t needed = off;

    if (ws_size < needed || NB > NBMAX || N > (1 << 20) ||
        (size_t)NB * CAP < (size_t)E / 2) {
        detect_zero_kernel<<<1, 1024, 0, stream>>>((const unsigned int*)rows,
                                                   flag, gcur, 0);
        (void)hipMemsetAsync(d_out, 0, (size_t)out_size * sizeof(float), stream);
        spmv_coo_kernel<<<8192, 256, 0, stream>>>(rows, cols, vals, x, out,
                                                  flag, E);
        return;
    }

    detect_zero_kernel<<<1, 1024, 0, stream>>>((const unsigned int*)rows,
                                               flag, gcur, NB);
    xconv_kernel<<<(N * 8 + 255) / 256, 256, 0, stream>>>(x, xh, N * 8);
    const int grid_c = (E + CHUNK - 1) / CHUNK;
    bscatter_kernel<<<grid_c, SCAT_T, 0, stream>>>(rows, cols, vals, gcur,
                                                   recs, flag, E);
    bsort_kernel<<<NB, 512, 0, stream>>>(gcur, recs, recs2, srange, N);
    const int grid_g = (N * 8 + 255) / 256;
    gather_kernel<<<grid_g, 256, 0, stream>>>(srange, recs2, xh, out, N);
}